// Round 1
// 226.018 us; speedup vs baseline: 1.0303x; 1.0303x over previous
//
#include <hip/hip_runtime.h>

// B=32, C=64, H=128, W=128, N_KNOTS=65. x is (B,C,H,W) row-major, 33,554,432 floats.
// Thread handles TWO vec4s (32 B); 256-thread block covers 2048 contiguous floats
// = 1/8 of one (b,c) channel slice (16384 floats), so the whole block shares ONE
// channel's coefficient table.
//
// LDS layout change vs previous version: instead of 65 scalars (3 ds_read_b32
// gathers/element, Gaussian-hotspot bank conflicts), store 64 overlapping
// aligned pairs p[i] = (c[i], c[i+1]).  Per element:
//   (c0,c1) = p[idx], (c1,c2) = p[idx+1]   -> 2 aligned b64 reads (compiler can
// merge into ds_read2_b64).  Bank-pair = idx mod 16; Gaussian(std=16) folded
// mod 16 is ~uniform -> conflict-free in expectation.
//
// Math (identical values to reference, ~1 ulp):
//   t  = x * inv_g                  (exact: g = 2^-3)
//   fl = clamp(floor(t), -32, 30)
//   s  = t - fl
//   out = c1 + u^2*(c0-c1)/2 + s^2*(c2-c1)/2,  u = s-1

typedef float vfloat4 __attribute__((ext_vector_type(4)));

__device__ __forceinline__ float spline_eval(float xx, const float2* lds_p,
                                             float inv_g, float flo, float fhi,
                                             int half) {
    float t   = xx * inv_g;
    float fl  = fminf(fmaxf(floorf(t), flo), fhi);   // [-32, 30]
    int   idx = half + (int)fl;                      // [0, 62]
    float s   = t - fl;                              // shift1 (unclamped x)
    float u   = s - 1.0f;
    float2 p0 = lds_p[idx];                          // (c[idx],   c[idx+1])
    float2 p1 = lds_p[idx + 1];                      // (c[idx+1], c[idx+2])
    float c0  = p0.x;
    float c1  = p0.y;
    float c2  = p1.y;
    float h0  = 0.5f * (c0 - c1);
    float h2  = 0.5f * (c2 - c1);
    return fmaf(u * u, h0, fmaf(s * s, h2, c1));
}

__global__ __launch_bounds__(256) void quad_spline_kernel(
    const vfloat4* __restrict__ x,
    const float*   __restrict__ coeffs,
    const float*   __restrict__ grid_p,
    const int*     __restrict__ zki,
    const int*     __restrict__ size_p,
    vfloat4*       __restrict__ out)
{
    __shared__ float2 lds_p[64];

    const int tid = threadIdx.x;
    const int v0  = blockIdx.x * 512 + tid;   // first vec4 index
    const int v1  = v0 + 256;                 // second vec4 index (coalesced)
    const int c   = (blockIdx.x >> 3) & 63;   // 8 blocks per (b,c) slice

    // Issue the streaming loads FIRST so HBM latency overlaps staging + sync.
    vfloat4 xa = __builtin_nontemporal_load(&x[v0]);
    vfloat4 xb = __builtin_nontemporal_load(&x[v1]);

    const float g    = grid_p[0];
    const int   size = size_p[0];
    const int   half = size >> 1;             // 32
    const int   base = zki[c] - half;         // = c * size

    if (tid < 64) {
        float a = coeffs[base + tid];
        float b = coeffs[base + tid + 1];
        lds_p[tid] = make_float2(a, b);       // p[i] = (c[i], c[i+1]), i in [0,63]
    }
    __syncthreads();

    const float inv_g = 1.0f / g;             // exact (g = 0.125)
    const float flo   = -(float)half;         // -32
    const float fhi   =  (float)(half - 2);   //  30

    vfloat4 ra, rb;
    ra.x = spline_eval(xa.x, lds_p, inv_g, flo, fhi, half);
    ra.y = spline_eval(xa.y, lds_p, inv_g, flo, fhi, half);
    ra.z = spline_eval(xa.z, lds_p, inv_g, flo, fhi, half);
    ra.w = spline_eval(xa.w, lds_p, inv_g, flo, fhi, half);
    rb.x = spline_eval(xb.x, lds_p, inv_g, flo, fhi, half);
    rb.y = spline_eval(xb.y, lds_p, inv_g, flo, fhi, half);
    rb.z = spline_eval(xb.z, lds_p, inv_g, flo, fhi, half);
    rb.w = spline_eval(xb.w, lds_p, inv_g, flo, fhi, half);

    __builtin_nontemporal_store(ra, &out[v0]);
    __builtin_nontemporal_store(rb, &out[v1]);
}

extern "C" void kernel_launch(void* const* d_in, const int* in_sizes, int n_in,
                              void* d_out, int out_size, void* d_ws, size_t ws_size,
                              hipStream_t stream) {
    const vfloat4* x      = (const vfloat4*)d_in[0];
    const float*   coeffs = (const float*)d_in[1];
    const float*   grid_p = (const float*)d_in[2];
    const int*     zki    = (const int*)d_in[3];
    const int*     size_p = (const int*)d_in[4];
    vfloat4*       out    = (vfloat4*)d_out;

    const int n4     = in_sizes[0] / 4;   // total vec4 count
    const int blocks = n4 / 512;          // 2 vec4 per thread, 256 threads/block

    quad_spline_kernel<<<blocks, 256, 0, stream>>>(x, coeffs, grid_p, zki, size_p, out);
}

// Round 2
// 224.185 us; speedup vs baseline: 1.0387x; 1.0082x over previous
//
#include <hip/hip_runtime.h>

// B=32, C=64, H=128, W=128, N_KNOTS=65. x is (B,C,H,W) row-major, 33,554,432 floats.
// Thread handles FOUR vec4s (64 B); 256-thread block covers 4096 contiguous floats
// = 1/4 of one (b,c) channel slice, so the whole block shares ONE channel's table.
//
// LDS now holds PRECOMPUTED per-interval polynomial coefficients:
//   out = a0 + a1*s + a2*s^2
//   a0 = (c0+c1)/2,  a1 = c1-c0,  a2 = (c0-2*c1+c2)/2
// One aligned ds_read_b128 per element (was 2x ds_read_b64), 2 FMAs for the
// polynomial (was 5 ops). idx Gaussian mod 8 -> uniform bank-group spread.
//
// Math equivalence with reference (established in prior rounds):
//   t  = x * inv_g            (exact: g = 2^-3, inv_g = 8)
//   fl = clamp(floor(t), -32, 30) == floor(clamp(x)/g)
//   s  = t - fl               == (x - fl*g)/g   (identical rounding)
//   reference frac-weighted sum == a0 + a1*s + a2*s^2 exactly (same polynomial)

typedef float vfloat4 __attribute__((ext_vector_type(4)));

__global__ __launch_bounds__(256) void quad_spline_kernel(
    const vfloat4* __restrict__ x,
    const float*   __restrict__ coeffs,
    const float*   __restrict__ grid_p,
    const int*     __restrict__ zki,
    const int*     __restrict__ size_p,
    vfloat4*       __restrict__ out)
{
    __shared__ vfloat4 lds_a[63];   // (a0, a1, a2, pad) per interval, idx in [0,62]

    const int tid   = threadIdx.x;
    const int vbase = blockIdx.x * 1024 + tid;  // 1024 vec4 per block
    const int c     = (blockIdx.x >> 2) & 63;   // 4 blocks per (b,c) slice

    // Issue all streaming loads FIRST so HBM latency overlaps staging + sync.
    vfloat4 x0 = __builtin_nontemporal_load(&x[vbase]);
    vfloat4 x1 = __builtin_nontemporal_load(&x[vbase + 256]);
    vfloat4 x2 = __builtin_nontemporal_load(&x[vbase + 512]);
    vfloat4 x3 = __builtin_nontemporal_load(&x[vbase + 768]);

    const float g    = grid_p[0];
    const int   size = size_p[0];
    const int   half = size >> 1;               // 32
    const int   base = zki[c] - half;           // = c * size

    if (tid < 63) {
        float c0 = coeffs[base + tid];
        float c1 = coeffs[base + tid + 1];
        float c2 = coeffs[base + tid + 2];
        vfloat4 a;
        a.x = 0.5f * (c0 + c1);                 // a0
        a.y = c1 - c0;                          // a1
        a.z = 0.5f * ((c0 - c1) + (c2 - c1));   // a2
        a.w = 0.0f;
        lds_a[tid] = a;
    }
    __syncthreads();

    const float inv_g = 1.0f / g;               // exact (g = 0.125)
    const float flo   = -(float)half;           // -32
    const float fhi   =  (float)(half - 2);     //  30

    #define SPLINE(xx, dst)                                            \
    {                                                                  \
        float t   = (xx) * inv_g;                                      \
        float fl  = fminf(fmaxf(floorf(t), flo), fhi);                 \
        int   idx = half + (int)fl;                                    \
        float s   = t - fl;                                            \
        vfloat4 a = lds_a[idx];                                        \
        (dst) = fmaf(s, fmaf(s, a.z, a.y), a.x);                       \
    }

    vfloat4 r0, r1, r2, r3;
    SPLINE(x0.x, r0.x) SPLINE(x0.y, r0.y) SPLINE(x0.z, r0.z) SPLINE(x0.w, r0.w)
    SPLINE(x1.x, r1.x) SPLINE(x1.y, r1.y) SPLINE(x1.z, r1.z) SPLINE(x1.w, r1.w)
    SPLINE(x2.x, r2.x) SPLINE(x2.y, r2.y) SPLINE(x2.z, r2.z) SPLINE(x2.w, r2.w)
    SPLINE(x3.x, r3.x) SPLINE(x3.y, r3.y) SPLINE(x3.z, r3.z) SPLINE(x3.w, r3.w)
    #undef SPLINE

    __builtin_nontemporal_store(r0, &out[vbase]);
    __builtin_nontemporal_store(r1, &out[vbase + 256]);
    __builtin_nontemporal_store(r2, &out[vbase + 512]);
    __builtin_nontemporal_store(r3, &out[vbase + 768]);
}

extern "C" void kernel_launch(void* const* d_in, const int* in_sizes, int n_in,
                              void* d_out, int out_size, void* d_ws, size_t ws_size,
                              hipStream_t stream) {
    const vfloat4* x      = (const vfloat4*)d_in[0];
    const float*   coeffs = (const float*)d_in[1];
    const float*   grid_p = (const float*)d_in[2];
    const int*     zki    = (const int*)d_in[3];
    const int*     size_p = (const int*)d_in[4];
    vfloat4*       out    = (vfloat4*)d_out;

    const int n4     = in_sizes[0] / 4;   // 8,388,608 vec4
    const int blocks = n4 / 1024;         // 8192 blocks, 4 vec4 per thread

    quad_spline_kernel<<<blocks, 256, 0, stream>>>(x, coeffs, grid_p, zki, size_p, out);
}